// Round 6
// baseline (56056.134 us; speedup 1.0000x reference)
//
#include <hip/hip_runtime.h>
#include <hip/hip_cooperative_groups.h>

namespace cg = cooperative_groups;

#define TT 2048
#define BB 32
#define DD 512
#define HH 512
#define NWG 64
#define NTHR 512

__global__ __launch_bounds__(NTHR, 1) void lstm_probe(
    const float* x,      // [B][T][D] f32
    const float* W,      // [D+H][4H] f32 row-major
    const float* bias,   // [4H] f32 (i|f|g|o)
    const float* h0,     // [B][H] f32
    const float* c0,     // [B][H] f32
    float* out,          // f32: outputs[B][T][H] | h_T[B][H] | c_T[B][H]
    float* hbuf)         // ws: 2 * B*H f32 double buffer
{
    cg::grid_group grid = cg::this_grid();
    __shared__ float w_lds[DD + HH][32];  // [k][gatecol]  gatecol = gate*8 + unit
    __shared__ float P2[2][BB][33];       // k-half partials

    const int wg  = blockIdx.x;   // 0..63, owns hidden units u0..u0+7
    const int tid = threadIdx.x;  // 0..511
    const int u0  = wg * 8;

    // ---- one-time: stage weight slice into LDS (reused for all 2048 steps)
    for (int it = 0; it < 64; ++it) {
        int idx = it * NTHR + tid;          // 0..32767
        int k = idx >> 5, c = idx & 31;     // k row, gate-col
        w_lds[k][c] = W[(size_t)k * 2048 + (size_t)(c >> 3) * HH + u0 + (c & 7)];
    }

    // ---- dot-phase ownership: batch dem, gate q, unit-quad g2, k-half kh
    const int dem = (tid >> 3) & 31;
    const int q   = (tid >> 1) & 3;
    const int g2  = tid & 1;
    const int kh  = tid >> 8;             // 0: k=0..511 (x), 1: k=512..1023 (h)
    const int wc  = q * 8 + g2 * 4;       // gate-col base this thread accumulates

    // ---- cell-phase ownership (tid < 256): (batch em, unit u0+ei)
    const int em = tid >> 3, ei = tid & 7;
    float bI = 0.f, bF = 0.f, bG = 0.f, bO = 0.f, cst = 0.f;
    if (tid < 256) {
        bI = bias[u0 + ei];
        bF = bias[HH + u0 + ei];
        bG = bias[2 * HH + u0 + ei];
        bO = bias[3 * HH + u0 + ei];
        cst = c0[em * HH + u0 + ei];
    }

    // ---- stage h0 -> hbuf buffer 0
    {
        int i = wg * NTHR + tid;
        if (i < BB * HH) hbuf[i] = h0[i];
    }
    grid.sync();

    int p = 0;  // h_t lives in hbuf[p]
    for (int t = 0; t < TT; ++t) {
        // ---- partial gate dots: 4 units of gate q over this thread's k-half
        float a0 = 0.f, a1 = 0.f, a2 = 0.f, a3 = 0.f;
        const float* asrc = kh ? (hbuf + (size_t)p * (BB * HH) + (size_t)dem * HH)
                               : (x + (size_t)dem * TT * DD + (size_t)t * DD);
        const int kbase = kh * DD;
        #pragma unroll 4
        for (int kk = 0; kk < 512; ++kk) {
            float a = asrc[kk];
            const float* wr = &w_lds[kbase + kk][wc];
            a0 += a * wr[0];
            a1 += a * wr[1];
            a2 += a * wr[2];
            a3 += a * wr[3];
        }
        P2[kh][dem][wc + 0] = a0;
        P2[kh][dem][wc + 1] = a1;
        P2[kh][dem][wc + 2] = a2;
        P2[kh][dem][wc + 3] = a3;
        __syncthreads();

        // ---- elementwise LSTM cell on tid < 256
        if (tid < 256) {
            float gi = bI + P2[0][em][ei]      + P2[1][em][ei];
            float gf = bF + P2[0][em][8 + ei]  + P2[1][em][8 + ei];
            float gg = bG + P2[0][em][16 + ei] + P2[1][em][16 + ei];
            float go = bO + P2[0][em][24 + ei] + P2[1][em][24 + ei];
            float si = 1.0f / (1.0f + __expf(-gi));
            float sf = 1.0f / (1.0f + __expf(-gf));
            float tg = tanhf(gg);
            float so = 1.0f / (1.0f + __expf(-go));
            cst = sf * cst + si * tg;
            float h = so * tanhf(cst);

            hbuf[(size_t)(1 - p) * (BB * HH) + em * HH + u0 + ei] = h;
            // f32 output, [B][T][H] per the reference's final transpose
            out[(size_t)em * TT * HH + (size_t)t * HH + u0 + ei] = h;
            if (t == TT - 1) {
                size_t ho = (size_t)BB * TT * HH;
                out[ho + em * HH + u0 + ei] = h;
                out[ho + (size_t)BB * HH + em * HH + u0 + ei] = cst;
            }
        }

        grid.sync();  // h_{t+1} visible everywhere; also guards P2/LDS reuse
        p ^= 1;
    }
}

extern "C" void kernel_launch(void* const* d_in, const int* in_sizes, int n_in,
                              void* d_out, int out_size, void* d_ws, size_t ws_size,
                              hipStream_t stream) {
    // Robust input assignment: detect by element count (immune to ordering).
    const float* x  = nullptr;
    const float* W  = nullptr;
    const float* b  = nullptr;
    const float* h0 = nullptr;
    const float* c0 = nullptr;
    for (int i = 0; i < n_in; ++i) {
        int sz = in_sizes[i];
        if      (sz == BB * TT * DD)       x = (const float*)d_in[i];  // 33554432
        else if (sz == (DD + HH) * 4 * HH) W = (const float*)d_in[i];  // 2097152
        else if (sz == 4 * HH)             b = (const float*)d_in[i];  // 2048
        else if (sz == BB * HH) {                                      // 16384 (h0 then c0)
            if (!h0) h0 = (const float*)d_in[i];
            else     c0 = (const float*)d_in[i];
        }
    }
    float* out  = (float*)d_out;
    float* hbuf = (float*)d_ws;   // 2 * 32*512 f32 = 128 KB

    void* args[] = {(void*)&x, (void*)&W, (void*)&b, (void*)&h0, (void*)&c0,
                    (void*)&out, (void*)&hbuf};
    hipLaunchCooperativeKernel((const void*)lstm_probe, dim3(NWG), dim3(NTHR),
                               args, 0, stream);
}

// Round 9
// 30146.506 us; speedup vs baseline: 1.8595x; 1.8595x over previous
//
#include <hip/hip_runtime.h>

#define TT 2048
#define BB 32
#define DD 512
#define HH 512
#define NWG 64
#define NTHR 256

typedef short s8v __attribute__((ext_vector_type(8)));
typedef float f4v __attribute__((ext_vector_type(4)));
typedef unsigned u4v __attribute__((ext_vector_type(4)));

union UF { u4v u; s8v s; };

__device__ __forceinline__ float asf(unsigned u) { return __uint_as_float(u); }

// v_cvt_pk_bf16_f32: D[15:0]=bf16(a) RNE, D[31:16]=bf16(b)
__device__ __forceinline__ unsigned cvtpk(float a, float b) {
    unsigned r;
    asm("v_cvt_pk_bf16_f32 %0, %1, %2" : "=v"(r) : "v"(a), "v"(b));
    return r;
}
// split pair (a,b) -> hi-packed u32 and lo-packed u32 (a ~= hi+lo to ~2^-16 rel)
__device__ __forceinline__ void split2(float a, float b, unsigned& hp, unsigned& lp) {
    hp = cvtpk(a, b);
    lp = cvtpk(a - asf(hp << 16), b - asf(hp & 0xFFFF0000u));
}

// ws layout (u32 units): hhi[2][BB*HH/2] | hlo[2][BB*HH/2] | flags[NWG*16]
__global__ void lstm_init(const float* __restrict__ h0,
                          unsigned* __restrict__ hhi,
                          unsigned* __restrict__ hlo,
                          unsigned* __restrict__ flags) {
    int j = blockIdx.x * blockDim.x + threadIdx.x;
    if (j < NWG * 16) flags[j] = 0u;
    if (j < BB * HH / 2) {
        unsigned hp, lp;
        split2(h0[2 * j], h0[2 * j + 1], hp, lp);
        hhi[j] = hp;   // buffer 0 (t=0); kernel-boundary sync makes this visible
        hlo[j] = lp;
    }
}

__global__ __launch_bounds__(NTHR, 1) void lstm_scan(
    const float* __restrict__ x,     // [B][T][D] f32
    const float* __restrict__ W,     // [1024][2048] f32 (rows 0..511 Wx, 512..1023 Wh)
    const float* __restrict__ bias,  // [2048] f32 (i|f|g|o)
    const float* __restrict__ c0,    // [B][H] f32
    float* __restrict__ out,         // f32: outputs[B][T][H] | h_T[B][H] | c_T[B][H]
    unsigned* hhi, unsigned* hlo,    // packed bf16-pair h buffers (NOT restrict: cross-WG shared)
    unsigned* flags)
{
    __shared__ float P[32][33];      // gates exchange: [batch][gatecol], gatecol = q*8+unit

    const int wg  = blockIdx.x;      // owns hidden units u0..u0+7
    const int tid = threadIdx.x;
    const int u0  = wg * 8;
    const int wv  = tid >> 6, ln = tid & 63;
    const int bh  = wv >> 1;         // batch half: A rows bh*16..+15
    const int ch  = wv & 1;          // gate-col half: B cols ch*16..+15
    const int fl  = ln & 15;         // A row / B col within 16
    const int fg  = ln >> 4;         // k-group: k = it*32 + fg*8 + j

    // ---- one-time: weight slice -> registers as RNE hi/lo bf16 fragments
    // frag it covers W rows it*32 + fg*8 + (0..7)  (0..511 = Wx, 512..1023 = Wh)
    s8v whi[32], wlo[32];
    {
        const int col  = ch * 16 + fl;                       // P col 0..31
        const int wcol = ((col >> 3) << 9) + u0 + (col & 7); // gate*512 + unit
        #pragma unroll
        for (int it = 0; it < 32; ++it) {
            float v[8];
            #pragma unroll
            for (int j = 0; j < 8; ++j)
                v[j] = W[(size_t)(it * 32 + fg * 8 + j) * 2048 + wcol];
            UF H, L;
            #pragma unroll
            for (int q = 0; q < 4; ++q) {
                unsigned hp, lp;
                split2(v[2 * q], v[2 * q + 1], hp, lp);
                H.u[q] = hp; L.u[q] = lp;
            }
            whi[it] = H.s; wlo[it] = L.s;
        }
    }

    // ---- cell ownership: (batch em, unit u0+ei)
    const int em = tid >> 3, ei = tid & 7;
    const float bI = bias[u0 + ei];
    const float bF = bias[HH + u0 + ei];
    const float bG = bias[2 * HH + u0 + ei];
    const float bO = bias[3 * HH + u0 + ei];
    float cst = c0[em * HH + u0 + ei];

    const int arow = bh * 16 + fl;                     // batch row this lane loads
    const float* xlane = x + (size_t)arow * TT * DD + fg * 8;
    const int hb = arow * (HH / 2) + fg * 4;           // u32 base into h buffers

    for (int t = 0; t < TT; ++t) {
        f4v acc  = {0.f, 0.f, 0.f, 0.f};
        f4v accl = {0.f, 0.f, 0.f, 0.f};

        // ---- x contribution (before the wait: hides under other WGs' lag)
        {
            const float* xs = xlane + (size_t)t * DD;
            #pragma unroll
            for (int it = 0; it < 16; ++it) {
                float4 f0 = *(const float4*)(xs + it * 32);
                float4 f1 = *(const float4*)(xs + it * 32 + 4);
                UF H, L;
                unsigned hp, lp;
                split2(f0.x, f0.y, hp, lp); H.u[0] = hp; L.u[0] = lp;
                split2(f0.z, f0.w, hp, lp); H.u[1] = hp; L.u[1] = lp;
                split2(f1.x, f1.y, hp, lp); H.u[2] = hp; L.u[2] = lp;
                split2(f1.z, f1.w, hp, lp); H.u[3] = hp; L.u[3] = lp;
                acc  = __builtin_amdgcn_mfma_f32_16x16x32_bf16(H.s, whi[it], acc, 0, 0, 0);
                accl = __builtin_amdgcn_mfma_f32_16x16x32_bf16(L.s, whi[it], accl, 0, 0, 0);
                accl = __builtin_amdgcn_mfma_f32_16x16x32_bf16(H.s, wlo[it], accl, 0, 0, 0);
            }
        }

        // ---- wait for h_t from all WGs (t=0: init kernel, kernel-boundary sync)
        if (t > 0) {
            if (tid < 64) {
                for (;;) {
                    unsigned v = __hip_atomic_load(&flags[tid * 16], __ATOMIC_RELAXED,
                                                   __HIP_MEMORY_SCOPE_AGENT);
                    if (__all((int)v >= t)) break;
                }
            }
            __syncthreads();
            __builtin_amdgcn_fence(__ATOMIC_ACQUIRE, "agent");
        }

        // ---- h contribution: MFMA-ready packed hi/lo fragments
        {
            const unsigned* hh = hhi + (size_t)(t & 1) * (BB * HH / 2);
            const unsigned* hl = hlo + (size_t)(t & 1) * (BB * HH / 2);
            #pragma unroll
            for (int it = 0; it < 16; ++it) {
                UF H, L;
                H.u = *(const u4v*)(hh + hb + it * 16);
                L.u = *(const u4v*)(hl + hb + it * 16);
                acc  = __builtin_amdgcn_mfma_f32_16x16x32_bf16(H.s, whi[16 + it], acc, 0, 0, 0);
                accl = __builtin_amdgcn_mfma_f32_16x16x32_bf16(L.s, whi[16 + it], accl, 0, 0, 0);
                accl = __builtin_amdgcn_mfma_f32_16x16x32_bf16(H.s, wlo[16 + it], accl, 0, 0, 0);
            }
        }

        // ---- C write: col=lane&15, row=(lane>>4)*4+reg (m89/m91-verified)
        #pragma unroll
        for (int r = 0; r < 4; ++r)
            P[bh * 16 + fg * 4 + r][ch * 16 + fl] = acc[r] + accl[r];
        __syncthreads();

        // ---- elementwise LSTM cell
        float gi = bI + P[em][ei];
        float gf = bF + P[em][8 + ei];
        float gg = bG + P[em][16 + ei];
        float go = bO + P[em][24 + ei];
        float si = 1.0f / (1.0f + __expf(-gi));
        float sf = 1.0f / (1.0f + __expf(-gf));
        float e2 = __expf(2.0f * fminf(fmaxf(gg, -15.f), 15.f));
        float tg = (e2 - 1.0f) / (e2 + 1.0f);
        float so = 1.0f / (1.0f + __expf(-go));
        cst = sf * cst + si * tg;
        float e2c = __expf(2.0f * fminf(fmaxf(cst, -15.f), 15.f));
        float h = so * (e2c - 1.0f) / (e2c + 1.0f);

        // ---- outputs (f32, [B][T][H] — r6-validated addressing)
        out[(size_t)em * TT * HH + (size_t)t * HH + u0 + ei] = h;
        if (t == TT - 1) {
            size_t ho = (size_t)BB * TT * HH;
            out[ho + em * HH + u0 + ei] = h;
            out[ho + (size_t)BB * HH + em * HH + u0 + ei] = cst;
        }

        // ---- publish h_{t+1} as packed hi/lo pairs (agent-visible)
        {
            float hn = __shfl_down(h, 1);
            if ((ei & 1) == 0) {
                unsigned hp, lp;
                split2(h, hn, hp, lp);
                int idx = em * (HH / 2) + ((u0 + ei) >> 1);
                unsigned* dh = hhi + (size_t)((t + 1) & 1) * (BB * HH / 2);
                unsigned* dl = hlo + (size_t)((t + 1) & 1) * (BB * HH / 2);
                __hip_atomic_store(&dh[idx], hp, __ATOMIC_RELAXED, __HIP_MEMORY_SCOPE_AGENT);
                __hip_atomic_store(&dl[idx], lp, __ATOMIC_RELAXED, __HIP_MEMORY_SCOPE_AGENT);
            }
        }

        __syncthreads();   // compiler emits vmcnt(0) drain: all waves' h stores visible
        if (tid == 0)
            __hip_atomic_store(&flags[wg * 16], (unsigned)(t + 1),
                               __ATOMIC_RELEASE, __HIP_MEMORY_SCOPE_AGENT);
    }
}

extern "C" void kernel_launch(void* const* d_in, const int* in_sizes, int n_in,
                              void* d_out, int out_size, void* d_ws, size_t ws_size,
                              hipStream_t stream) {
    const float* x  = nullptr;
    const float* W  = nullptr;
    const float* b  = nullptr;
    const float* h0 = nullptr;
    const float* c0 = nullptr;
    for (int i = 0; i < n_in; ++i) {
        int sz = in_sizes[i];
        if      (sz == BB * TT * DD)       x = (const float*)d_in[i];
        else if (sz == (DD + HH) * 4 * HH) W = (const float*)d_in[i];
        else if (sz == 4 * HH)             b = (const float*)d_in[i];
        else if (sz == BB * HH) { if (!h0) h0 = (const float*)d_in[i];
                                  else     c0 = (const float*)d_in[i]; }
    }
    float* out = (float*)d_out;
    unsigned* hhi   = (unsigned*)d_ws;                 // 2 * 8192 u32
    unsigned* hlo   = hhi + 2 * (BB * HH / 2);         // 2 * 8192 u32
    unsigned* flags = hlo + 2 * (BB * HH / 2);         // 64 * 16 u32

    lstm_init<<<64, NTHR, 0, stream>>>(h0, hhi, hlo, flags);

    // Plain launch: 64 blocks on a 256-CU idle chip are trivially co-resident;
    // r8's hipLaunchCooperativeKernel silently failed (zero-output signature).
    lstm_scan<<<NWG, NTHR, 0, stream>>>(x, W, b, c0, out, hhi, hlo, flags);
}